// Round 5
// baseline (79.630 us; speedup 1.0000x reference)
//
#include <hip/hip_runtime.h>

#define NBATCH 16
#define CIN_ 128
#define COUT_ 128
#define H_ 128
#define W_ 128
#define TH 4               // output rows per tile
#define NR (TH + 2)        // staged input rows
#define CPITCH 34          // ci pitch in LDS tile (17-word stride -> conflict-light reads)
#define TILE_ELEMS (NR * 130 * CPITCH)

typedef short bf16x8 __attribute__((ext_vector_type(8)));
typedef float f32x4 __attribute__((ext_vector_type(4)));

__device__ __forceinline__ unsigned short f32_to_bf16(float f) {
  unsigned int u = __float_as_uint(f);
  u += 0x7fffu + ((u >> 16) & 1u);   // round-to-nearest-even
  return (unsigned short)(u >> 16);
}

// ---------------- kernel 1: decode block mask -> active lists ----------------
__global__ void make_lists_k(const float* __restrict__ mask, int* __restrict__ lists) {
  if (threadIdx.x == 0) {
    for (int i = 0; i < 20; ++i) lists[i] = 0;
    for (int ob = 0; ob < 4; ++ob) {
      int c = 0;
      for (int ib = 0; ib < 4; ++ib) {
        float v = mask[(size_t)((ob * 32) * CIN_ + ib * 32) * 9];
        if (v != 0.0f) { lists[4 + ob * 4 + c] = ib; ++c; }
      }
      lists[ob] = c;
    }
  }
}

// ---------------- kernel 2: pack masked weights to bf16, MFMA A-layout -------
// wpack[ob][slot][khkw][co(32)][ci(32)]  (ci contiguous)
__global__ __launch_bounds__(256) void pack_w_k(const float* __restrict__ weight,
                                                const float* __restrict__ mask,
                                                const int* __restrict__ lists,
                                                unsigned short* __restrict__ wpack) {
  const int khkw = blockIdx.x;   // 0..8
  const int slot = blockIdx.y;   // 0..3
  const int ob   = blockIdx.z;   // 0..3
  if (slot >= lists[ob]) return;
  const int ib = lists[4 + ob * 4 + slot];
  const int kh = khkw / 3, kw = khkw % 3;
  for (int e = threadIdx.x; e < 1024; e += 256) {
    const int co = e >> 5, ci = e & 31;
    const int cog = ob * 32 + co, cig = ib * 32 + ci;
    const size_t widx = ((size_t)(cog * CIN_ + cig) * 3 + kh) * 3 + kw;
    const float v = weight[widx] * mask[widx];
    wpack[(size_t)((ob * 4 + slot) * 9 + khkw) * 1024 + e] = f32_to_bf16(v);
  }
}

// ---------------- kernel 3: producer/consumer fused conv ---------------------
// 256 WGs x 512 threads. waves 0-3 consume (MFMA), waves 4-7 produce (stage).
// Each WG owns 8 consecutive linear tiles t = wg*8+i:
//   ob = i&3, b = (wg*2 + (i>>2)) & 15, h0 = (wg>>3)*TH
// Unit stream = per tile: max(cnt,1) units (cnt==0 -> bias-only unit).
// Double-buffered LDS; one barrier per unit; producers stage unit k+1 while
// consumers compute unit k.
__global__ __launch_bounds__(512, 2) void conv_pc_k(const float* __restrict__ x,
                                                    const unsigned short* __restrict__ wpack,
                                                    const int* __restrict__ lists,
                                                    const float* __restrict__ bias,
                                                    float* __restrict__ out) {
  __shared__ unsigned short xs[2][TILE_ELEMS];   // 2 x 53 KB

  const int tid = threadIdx.x;
  const int wg  = blockIdx.x;                    // 0..255
  const bool is_prod = tid >= 256;

  int cnts[4];
#pragma unroll
  for (int o = 0; o < 4; ++o) cnts[o] = lists[o];

  // total units for this WG (ob pattern = i&3, independent of wg)
  int U = 0;
#pragma unroll
  for (int i = 0; i < 8; ++i) { int c = cnts[i & 3]; U += (c > 0 ? c : 1); }

  const int h0 = (wg >> 3) * TH;

  // ---------------- producer staging (stages unit (i,s) into buf) ----------
  const int ptid = tid & 255;
  const int q = ptid & 31;        // w quad
  const int g = ptid >> 5;        // 0..7

  // ---------------- consumer ids -------------------------------------------
  const int lane = tid & 63;
  const int wave = tid >> 6;      // consumers: 0..3
  const int wl   = lane & 15;
  const int kg   = lane >> 4;
  const int w0   = (wave & 3) * 32;

  f32x4 acc[TH][2][2] = {};

  // unit pointers: (pi,ps) for producer (next unit to stage), (ci_,cs) consumer
  int pi = 0, ps = 0;
  int ci_ = 0, cs = 0;

  // ---- prologue: stage unit 0 into buf 0 ----
  if (is_prod) {
    const int ob = pi & 3;
    const int c  = cnts[ob];
    if (c > 0) {
      const int b  = (wg * 2 + (pi >> 2)) & 15;
      const int ib = lists[4 + ob * 4 + ps];
      unsigned short* buf = xs[0];
      const float* xbase = x + ((size_t)b * CIN_ + ib * 32) * H_ * W_ + q * 4;
#pragma unroll
      for (int it = 0; it < 12; ++it) {
        const int combo = it * 8 + g;
        const int r  = combo >> 4;
        const int cp = combo & 15;
        const int row = h0 - 1 + r;
        const bool rv = (row >= 0) && (row < H_);
        const float* src = xbase + ((size_t)(cp * 2) * H_ + (rv ? row : 0)) * W_;
        f32x4 va = *(const f32x4*)src;
        f32x4 vb = *(const f32x4*)(src + (size_t)H_ * W_);
        unsigned int* xd = (unsigned int*)(buf + (r * 130 + q * 4 + 1) * CPITCH + cp * 2);
#pragma unroll
        for (int j = 0; j < 4; ++j) {
          unsigned int lo = rv ? (unsigned int)f32_to_bf16(va[j]) : 0u;
          unsigned int hi = rv ? (unsigned int)f32_to_bf16(vb[j]) : 0u;
          xd[j * (CPITCH / 2)] = lo | (hi << 16);
        }
      }
      for (int e = ptid; e < NR * 2 * 32; e += 256) {
        const int r = e >> 6, edge = (e >> 5) & 1, cc = e & 31;
        buf[(r * 130 + (edge ? 129 : 0)) * CPITCH + cc] = 0;
      }
    }
  }
  __syncthreads();

  // ---- main pipeline ----
  for (int k = 0; k < U; ++k) {
    if (is_prod) {
      // advance producer pointer to unit k+1, stage it into buf[(k+1)&1]
      {
        const int ob = pi & 3;
        const int nu = (cnts[ob] > 0 ? cnts[ob] : 1);
        if (ps + 1 < nu) ++ps; else { ++pi; ps = 0; }
      }
      if (k + 1 < U) {
        const int ob = pi & 3;
        const int c  = cnts[ob];
        if (c > 0) {
          const int b  = (wg * 2 + (pi >> 2)) & 15;
          const int ib = lists[4 + ob * 4 + ps];
          unsigned short* buf = xs[(k + 1) & 1];
          const float* xbase = x + ((size_t)b * CIN_ + ib * 32) * H_ * W_ + q * 4;
#pragma unroll
          for (int it = 0; it < 12; ++it) {
            const int combo = it * 8 + g;
            const int r  = combo >> 4;
            const int cp = combo & 15;
            const int row = h0 - 1 + r;
            const bool rv = (row >= 0) && (row < H_);
            const float* src = xbase + ((size_t)(cp * 2) * H_ + (rv ? row : 0)) * W_;
            f32x4 va = *(const f32x4*)src;
            f32x4 vb = *(const f32x4*)(src + (size_t)H_ * W_);
            unsigned int* xd = (unsigned int*)(buf + (r * 130 + q * 4 + 1) * CPITCH + cp * 2);
#pragma unroll
            for (int j = 0; j < 4; ++j) {
              unsigned int lo = rv ? (unsigned int)f32_to_bf16(va[j]) : 0u;
              unsigned int hi = rv ? (unsigned int)f32_to_bf16(vb[j]) : 0u;
              xd[j * (CPITCH / 2)] = lo | (hi << 16);
            }
          }
          for (int e = ptid; e < NR * 2 * 32; e += 256) {
            const int r = e >> 6, edge = (e >> 5) & 1, cc = e & 31;
            buf[(r * 130 + (edge ? 129 : 0)) * CPITCH + cc] = 0;
          }
        }
      }
    } else {
      // ---- consumer: compute unit k (tile (ci_), slot cs) ----
      const int ob  = ci_ & 3;
      const int cnt = cnts[ob];
      const int b   = (wg * 2 + (ci_ >> 2)) & 15;

      if (cnt > 0) {
        const int s = cs;
        const unsigned short* xsb = xs[k & 1];

        // hoist 18 A fragments for this (ob, s)
        const unsigned short* wk =
            wpack + (size_t)((ob * 4 + s) * 9) * 1024 + wl * 32 + kg * 8;
        bf16x8 a[3][3][2];
#pragma unroll
        for (int kh = 0; kh < 3; ++kh)
#pragma unroll
          for (int kw = 0; kw < 3; ++kw) {
            a[kh][kw][0] = *(const bf16x8*)(wk + (kh * 3 + kw) * 1024);
            a[kh][kw][1] = *(const bf16x8*)(wk + (kh * 3 + kw) * 1024 + 16 * 32);
          }

#pragma unroll
        for (int ridx = 0; ridx < NR; ++ridx) {
          bf16x8 bf[2][3];
#pragma unroll
          for (int ni = 0; ni < 2; ++ni)
#pragma unroll
            for (int kw = 0; kw < 3; ++kw)
              bf[ni][kw] = *(const bf16x8*)(xsb + (ridx * 130 + w0 + ni * 16 + wl + kw) * CPITCH + kg * 8);

#pragma unroll
          for (int kh = 0; kh < 3; ++kh) {
            const int hi = ridx - kh;
            if (hi < 0 || hi >= TH) continue;
#pragma unroll
            for (int kw = 0; kw < 3; ++kw) {
              acc[hi][0][0] = __builtin_amdgcn_mfma_f32_16x16x32_bf16(a[kh][kw][0], bf[0][kw], acc[hi][0][0], 0, 0, 0);
              acc[hi][0][1] = __builtin_amdgcn_mfma_f32_16x16x32_bf16(a[kh][kw][0], bf[1][kw], acc[hi][0][1], 0, 0, 0);
              acc[hi][1][0] = __builtin_amdgcn_mfma_f32_16x16x32_bf16(a[kh][kw][1], bf[0][kw], acc[hi][1][0], 0, 0, 0);
              acc[hi][1][1] = __builtin_amdgcn_mfma_f32_16x16x32_bf16(a[kh][kw][1], bf[1][kw], acc[hi][1][1], 0, 0, 0);
            }
          }
        }
      }

      // epilogue on last unit of tile (covers bias-only: acc stays zero)
      const int nu = (cnt > 0 ? cnt : 1);
      if (cs == nu - 1) {
#pragma unroll
        for (int mi = 0; mi < 2; ++mi)
#pragma unroll
          for (int j = 0; j < 4; ++j) {
            const int co = mi * 16 + kg * 4 + j;
            const float bv = bias[ob * 32 + co];
#pragma unroll
            for (int hh = 0; hh < TH; ++hh) {
              float* yrow = out + ((size_t)(b * COUT_ + ob * 32 + co) * H_ + h0 + hh) * W_;
              yrow[w0 + wl]      = acc[hh][mi][0][j] + bv;
              yrow[w0 + wl + 16] = acc[hh][mi][1][j] + bv;
            }
          }
#pragma unroll
        for (int hh = 0; hh < TH; ++hh)
#pragma unroll
          for (int mi = 0; mi < 2; ++mi)
#pragma unroll
            for (int ni = 0; ni < 2; ++ni)
              acc[hh][mi][ni] = f32x4{0.f, 0.f, 0.f, 0.f};
      }

      // advance consumer pointer
      if (cs + 1 < nu) ++cs; else { ++ci_; cs = 0; }
    }
    __syncthreads();
  }
}

extern "C" void kernel_launch(void* const* d_in, const int* in_sizes, int n_in,
                              void* d_out, int out_size, void* d_ws, size_t ws_size,
                              hipStream_t stream) {
  const float* x      = (const float*)d_in[0];
  const float* weight = (const float*)d_in[1];
  const float* bias   = (const float*)d_in[2];
  const float* mask   = (const float*)d_in[3];
  float* out = (float*)d_out;

  int* lists = (int*)d_ws;
  unsigned short* wpack = (unsigned short*)((char*)d_ws + 4096);

  make_lists_k<<<1, 64, 0, stream>>>(mask, lists);
  pack_w_k<<<dim3(9, 4, 4), 256, 0, stream>>>(weight, mask, lists, wpack);
  conv_pc_k<<<256, 512, 0, stream>>>(x, wpack, lists, bias, out);
}